// Round 1
// baseline (584.781 us; speedup 1.0000x reference)
//
#include <hip/hip_runtime.h>
#include <hip/hip_bf16.h>

using f32x4  = __attribute__((ext_vector_type(4))) float;
using bf16x8 = __attribute__((ext_vector_type(8))) short;
using s16x4  = __attribute__((ext_vector_type(4))) short;

typedef const __attribute__((address_space(1))) void* gptr_t;
typedef __attribute__((address_space(3))) void* lptr_t;

__device__ __forceinline__ short f2b(float f) {
  __hip_bfloat16 h = __float2bfloat16(f);
  return __builtin_bit_cast(short, h);
}

__device__ __forceinline__ float tanh_fast(float x) {
  // tanh(x) = 1 - 2/(exp(2x)+1); exact at +/-inf: e=inf -> 1, e=0 -> -1
  float e = __expf(2.0f * x);
  return 1.0f - 2.0f * __builtin_amdgcn_rcpf(e + 1.0f);
}

// ---- kernel 1: Wi f32 -> bf16 bits (262144 elems; 256 blk * 256 thr * 4)
__global__ void cvt_wi_kernel(const float* __restrict__ w, short* __restrict__ o) {
  int i = (blockIdx.x * blockDim.x + threadIdx.x) * 4;
  f32x4 v = *reinterpret_cast<const f32x4*>(w + i);
  s16x4 h;
  h[0] = f2b(v[0]); h[1] = f2b(v[1]); h[2] = f2b(v[2]); h[3] = f2b(v[3]);
  *reinterpret_cast<s16x4*>(o + i) = h;
}

// ---- kernel 2: cbias[n] = bi[n] + bh[n] + dot(h0, Wh[n,:]); also scalar out = 1
__global__ void bias_kernel(const float* __restrict__ Wh, const float* __restrict__ bh,
                            const float* __restrict__ bi, const float* __restrict__ h0,
                            float* __restrict__ cbias, float* __restrict__ scalar_out) {
  int n = blockIdx.x, l = threadIdx.x;  // 512 blocks x 64 threads
  float s = 0.f;
  for (int k = l; k < 512; k += 64) s += h0[k] * Wh[n * 512 + k];
  for (int off = 32; off; off >>= 1) s += __shfl_down(s, off);
  if (l == 0) {
    cbias[n] = s + bi[n] + bh[n];
    if (n == 0) *scalar_out = 1.0f;
  }
}

// ---- kernel 3: C[131072,512] = tanh( X[131072,512] @ Wb^T + cbias )
// 128x128 tile, BK=64, 4 waves of 64x64, mfma_f32_16x16x32_bf16.
// A: reg-staged with fused f32->bf16 cvt, XOR-swizzled ds_write.
// B: global_load_lds(16B) from pre-converted bf16 Wi, source pre-swizzled.
// LDS tiles [128][64] bf16; 16B chunk c of row r stored at slot (c ^ (r&7)).
__global__ __launch_bounds__(256) void rnn_gemm(const float* __restrict__ X,
                                                const short* __restrict__ Wb,
                                                const float* __restrict__ cbias,
                                                float* __restrict__ out) {
  alignas(16) __shared__ short As[128 * 64];
  alignas(16) __shared__ short Bs[128 * 64];

  const int tid  = threadIdx.x;
  const int lane = tid & 63;
  const int wave = tid >> 6;
  const int bid  = blockIdx.x;
  const int nb   = bid & 3;    // N fast: 4 consecutive blocks share A rows (L2/L3)
  const int mb   = bid >> 2;
  const int wm   = wave >> 1;
  const int wn   = wave & 1;

  f32x4 acc[4][4] = {};

  // A staging: thread t -> row t>>1, k-half (t&1)*32 (32 f32 = 128B gmem, 64B lds)
  const int a_row = tid >> 1;
  const int a_kh  = (tid & 1) * 32;
  const float* gA = X + (size_t)(mb * 128 + a_row) * 512 + a_kh;

  f32x4 av[8];
#pragma unroll
  for (int j = 0; j < 8; ++j) av[j] = *reinterpret_cast<const f32x4*>(gA + j * 4);

  const int b_r_off = lane >> 3;  // row within 8-row glds region
  const int b_c     = lane & 7;   // dest 16B slot within row

  for (int kt = 0; kt < 8; ++kt) {
    // ---- write A tile (convert + swizzle). chunks (t&1)*4+j, j=0..3
    {
      const int c_base = (tid & 1) * 4;
      const int rx = a_row & 7;
#pragma unroll
      for (int j = 0; j < 4; ++j) {
        f32x4 lo = av[2 * j], hi = av[2 * j + 1];
        bf16x8 h;
        h[0] = f2b(lo[0]); h[1] = f2b(lo[1]); h[2] = f2b(lo[2]); h[3] = f2b(lo[3]);
        h[4] = f2b(hi[0]); h[5] = f2b(hi[1]); h[6] = f2b(hi[2]); h[7] = f2b(hi[3]);
        int slot = (c_base + j) ^ rx;
        *reinterpret_cast<bf16x8*>(As + a_row * 64 + slot * 8) = h;
      }
    }
    // ---- B tile: 4 glds calls/wave, 1024B each (dest linear, source pre-swizzled)
#pragma unroll
    for (int c = 0; c < 4; ++c) {
      int call = wave * 4 + c;
      int r = call * 8 + b_r_off;
      const short* src = Wb + (size_t)(nb * 128 + r) * 512 + kt * 64 + ((b_c ^ (r & 7)) * 8);
      __builtin_amdgcn_global_load_lds((gptr_t)src, (lptr_t)(Bs + call * 512), 16, 0, 0);
    }
    __syncthreads();  // drains vmcnt (glds) + lgkm (ds_write)

    if (kt < 7) {     // prefetch next A f32 block; lands during MFMA
#pragma unroll
      for (int j = 0; j < 8; ++j)
        av[j] = *reinterpret_cast<const f32x4*>(gA + (kt + 1) * 64 + j * 4);
    }

    // ---- compute: 2 k-substeps x (4+4 ds_read_b128 + 16 MFMA)
#pragma unroll
    for (int ks = 0; ks < 2; ++ks) {
      bf16x8 afr[4], bfr[4];
#pragma unroll
      for (int mi = 0; mi < 4; ++mi) {
        int r = wm * 64 + mi * 16 + (lane & 15);
        int slot = (ks * 4 + (lane >> 4)) ^ (r & 7);
        afr[mi] = *reinterpret_cast<const bf16x8*>(As + r * 64 + slot * 8);
      }
#pragma unroll
      for (int ni = 0; ni < 4; ++ni) {
        int r = wn * 64 + ni * 16 + (lane & 15);
        int slot = (ks * 4 + (lane >> 4)) ^ (r & 7);
        bfr[ni] = *reinterpret_cast<const bf16x8*>(Bs + r * 64 + slot * 8);
      }
#pragma unroll
      for (int mi = 0; mi < 4; ++mi)
#pragma unroll
        for (int ni = 0; ni < 4; ++ni)
          acc[mi][ni] = __builtin_amdgcn_mfma_f32_16x16x32_bf16(afr[mi], bfr[ni],
                                                                acc[mi][ni], 0, 0, 0);
    }
    __syncthreads();
  }

  // ---- epilogue: bias + tanh, f32 stores (C/D: col=lane&15, row=4*(lane>>4)+i)
  float cb[4];
#pragma unroll
  for (int ni = 0; ni < 4; ++ni)
    cb[ni] = cbias[nb * 128 + wn * 64 + ni * 16 + (lane & 15)];

#pragma unroll
  for (int mi = 0; mi < 4; ++mi) {
    int r0 = mb * 128 + wm * 64 + mi * 16 + ((lane >> 4) << 2);
#pragma unroll
    for (int i = 0; i < 4; ++i) {
      size_t rowbase = (size_t)(r0 + i) * 512 + nb * 128 + wn * 64 + (lane & 15);
#pragma unroll
      for (int ni = 0; ni < 4; ++ni)
        out[rowbase + ni * 16] = tanh_fast(acc[mi][ni][i] + cb[ni]);
    }
  }
}

extern "C" void kernel_launch(void* const* d_in, const int* in_sizes, int n_in,
                              void* d_out, int out_size, void* d_ws, size_t ws_size,
                              hipStream_t stream) {
  const float* x  = (const float*)d_in[0];   // [64,2048,512]
  const float* Wi = (const float*)d_in[1];   // [512,512]
  const float* bi = (const float*)d_in[2];   // [512]
  const float* Wh = (const float*)d_in[3];   // [512,512]
  const float* bh = (const float*)d_in[4];   // [512]
  const float* h0 = (const float*)d_in[5];   // [1,512]
  float* out = (float*)d_out;                // 64*2048*512 floats + 1 scalar

  short* wi_bf = (short*)d_ws;                       // 524288 B
  float* cbias = (float*)((char*)d_ws + 524288);     // 2048 B

  hipLaunchKernelGGL(cvt_wi_kernel, dim3(256), dim3(256), 0, stream, Wi, wi_bf);
  hipLaunchKernelGGL(bias_kernel, dim3(512), dim3(64), 0, stream,
                     Wh, bh, bi, h0, cbias, out + (out_size - 1));
  hipLaunchKernelGGL(rnn_gemm, dim3(4096), dim3(256), 0, stream, x, wi_bf, cbias, out);
}